// Round 5
// baseline (406.573 us; speedup 1.0000x reference)
//
#include <hip/hip_runtime.h>
#include <hip/hip_bf16.h>

// GAT 3-layer: N=40000, E=400000 (+self-loops), H=4, HID=64, NCLS=121, F_IN=50.
// Round 15: attn latency attack. (1) edge_p restored as a streaming pass (CSR
// order): the scattered al4 gather + exp runs with 400K-thread MLP; attn reads
// p4 linearly. (2) attn64/attn121 edge loops are 3-stage software pipelines:
// csr[j+4] and F8/feat[src[j+2]] in flight while edge j is FMA'd (4 gathers
// outstanding per wave, was 2, and no dependent exp in the loop). Keeps all
// round-14 wins: fp8 epilogue fusion in layer-3 GEMM, no convert_f8 pass,
// round-1 GEMM core, XCD swizzle, LDS-staged fp32 out rows.

#define NNODES 40000
#define MPAD   40064    // 313 * 128
#define NEDGES 400000
#define FIN    50
#define NHEAD  4
#define SCANB  157      // ceil(40000/256)
#define N4     160000   // NNODES * NHEAD

typedef __attribute__((ext_vector_type(8))) short short8;
typedef __attribute__((ext_vector_type(4))) float float4v;
typedef __attribute__((ext_vector_type(2))) float float2v;
typedef __attribute__((ext_vector_type(4))) unsigned short ushort4v;
typedef __attribute__((ext_vector_type(8))) unsigned short ushort8v;
typedef __attribute__((ext_vector_type(2))) unsigned int uint2v;
typedef __attribute__((ext_vector_type(4))) unsigned int uint4v;

__device__ inline unsigned short f2bf(float f) {   // round-to-nearest-even bf16
    union { float f; unsigned u; } v; v.f = f;
    unsigned r = v.u + 0x7fff + ((v.u >> 16) & 1);
    return (unsigned short)(r >> 16);
}
__device__ inline float bf2f(unsigned short u) {
    union { unsigned u; float f; } v; v.u = ((unsigned)u) << 16; return v.f;
}
__device__ inline float lrelu(float x) { return x >= 0.f ? x : 0.2f * x; }

// async global->LDS, 16B per lane, wave-uniform LDS base + lane*16 (linear dest)
typedef __attribute__((address_space(3))) unsigned int lds_u32;
typedef __attribute__((address_space(1))) const unsigned int glb_u32;
__device__ __forceinline__ void gl2lds16(const short* g, short* l) {
    __builtin_amdgcn_global_load_lds((glb_u32*)g, (lds_u32*)l, 16, 0, 0);
}

// ---------------------------------------------------------------- CSR build
__global__ void hist_kernel(const int* __restrict__ dst, int* __restrict__ counts, int E) {
    int i = blockIdx.x * blockDim.x + threadIdx.x;
    if (i < E) atomicAdd(&counts[dst[i]], 1);
}

__global__ __launch_bounds__(256) void scan_local(const int* __restrict__ counts,
                                                  int* __restrict__ offsets,
                                                  int* __restrict__ partials) {
    __shared__ int sh[256];
    int b = blockIdx.x, t = threadIdx.x, i = b * 256 + t;
    int v = (i < NNODES) ? counts[i] : 0;
    sh[t] = v;
    __syncthreads();
    #pragma unroll
    for (int off = 1; off < 256; off <<= 1) {
        int u = (t >= off) ? sh[t - off] : 0;
        __syncthreads();
        sh[t] += u;
        __syncthreads();
    }
    if (i < NNODES) offsets[i] = sh[t] - v;     // local exclusive
    if (t == 255) partials[b] = sh[255];
}

__global__ __launch_bounds__(256) void scan_partials(int* __restrict__ partials,
                                                     int* __restrict__ pexcl) {
    __shared__ int sh[256];
    int t = threadIdx.x;
    int v = (t < SCANB) ? partials[t] : 0;
    sh[t] = v;
    __syncthreads();
    #pragma unroll
    for (int off = 1; off < 256; off <<= 1) {
        int u = (t >= off) ? sh[t - off] : 0;
        __syncthreads();
        sh[t] += u;
        __syncthreads();
    }
    pexcl[t] = sh[t] - v;
}

__global__ __launch_bounds__(256) void scan_carry(int* __restrict__ offsets,
                                                  const int* __restrict__ pexcl) {
    int b = blockIdx.x, i = b * 256 + threadIdx.x;
    if (i < NNODES) offsets[i] += pexcl[b];
}

// mutates offsets: after this, offsets[d] = end(d); beg(d) = offsets[d-1] (0 for d=0)
__global__ void scatter_kernel(const int* __restrict__ src, const int* __restrict__ dst,
                               int* __restrict__ offsets,
                               int* __restrict__ csr_src, int* __restrict__ csr_dst, int E) {
    int i = blockIdx.x * blockDim.x + threadIdx.x;
    if (i < E) {
        int d = dst[i];
        int pos = atomicAdd(&offsets[d], 1);
        csr_src[pos] = src[i];
        csr_dst[pos] = d;
    }
}

// per-edge softmax numerators, CSR order, streaming (massive MLP for the
// scattered al4 gathers + exp). FULL=1 adds the half-1 planes (layer 3).
template<int FULL>
__global__ void edge_p(const float* __restrict__ al4,
                       const int* __restrict__ csr_src, const int* __restrict__ csr_dst,
                       float* __restrict__ p4, int E) {
    int j = blockIdx.x * blockDim.x + threadIdx.x;
    if (j >= E) return;
    int s = csr_src[j], d = csr_dst[j];
    float4v a0 = *(const float4v*)&al4[s * 4];
    float4v b0 = *(const float4v*)&al4[N4 + d * 4];
    float4v lg;
    lg.x = a0.x + b0.x; lg.y = a0.y + b0.y; lg.z = a0.z + b0.z; lg.w = a0.w + b0.w;
    if (FULL) {
        float4v a1 = *(const float4v*)&al4[2 * N4 + s * 4];
        float4v b1 = *(const float4v*)&al4[3 * N4 + d * 4];
        lg.x += a1.x + b1.x; lg.y += a1.y + b1.y; lg.z += a1.z + b1.z; lg.w += a1.w + b1.w;
    }
    float4v p;
    p.x = __expf(lrelu(lg.x));
    p.y = __expf(lrelu(lg.y));
    p.z = __expf(lrelu(lg.z));
    p.w = __expf(lrelu(lg.w));
    *(float4v*)&p4[(size_t)j * 4] = p;
}

// ---------------------------------------------------------------- converts
__global__ void convert_x(const float* __restrict__ x, short* __restrict__ xb) {
    int i = blockIdx.x * blockDim.x + threadIdx.x;   // over MPAD*64
    if (i >= MPAD * 64) return;
    int r = i >> 6, k = i & 63;
    float v = (r < NNODES && k < FIN) ? x[r * FIN + k] : 0.f;
    xb[i] = f2bf(v);
}

// fused: wc1 = [W1^T|Wr1^T] (Kpad 64), wc2 = [W2^T|Wr2^T] (Kpad 256)
__global__ void convert_pack1(const float* __restrict__ W1, const float* __restrict__ Wr1,
                              const float* __restrict__ W2, const float* __restrict__ Wr2,
                              short* __restrict__ wc1, short* __restrict__ wc2) {
    int i = blockIdx.x * blockDim.x + threadIdx.x;
    if (i < 32768) {
        const float* W = (i < 16384) ? W1 : Wr1;
        int j = i & 16383;
        int n = j >> 6, k = j & 63;
        wc1[i] = f2bf((k < FIN) ? W[k * 256 + n] : 0.f);
    } else if (i < 163840) {
        int j = (i - 32768) & 65535;
        const float* W = (i < 98304) ? W2 : Wr2;
        int n = j >> 8, k = j & 255;
        wc2[(i - 32768)] = f2bf(W[k * 256 + n]);
    }
}

// fused: wc3 rows 0-511 = W3^T head-padded, rows 512-639 = Wr3^T; a3 pads [4][128]
__global__ void convert_pack2(const float* __restrict__ W3, const float* __restrict__ Wr3,
                              const float* __restrict__ a3s, const float* __restrict__ a3d,
                              short* __restrict__ wc3,
                              float* __restrict__ a3sp, float* __restrict__ a3dp) {
    int i = blockIdx.x * blockDim.x + threadIdx.x;
    if (i < 131072) {
        int j = i >> 8, k = i & 255;
        int h = j >> 7, c = j & 127;
        wc3[i] = f2bf((c < 121) ? W3[k * 484 + h * 121 + c] : 0.f);
    } else if (i < 163840) {
        int j = i - 131072;
        int n = j >> 8, k = j & 255;
        wc3[131072 + j] = f2bf((n < 121) ? Wr3[k * 121 + n] : 0.f);
    } else if (i < 164864) {
        int j = i - 163840;
        int which = j >> 9; int jj = j & 511;
        int h = jj >> 7, c = jj & 127;
        float v = (c < 121) ? (which ? a3d[h * 121 + c] : a3s[h * 121 + c]) : 0.f;
        (which ? a3dp : a3sp)[jj] = v;
    }
}

// ---------------------------------------------------------------- fused MFMA GEMM
// Round-1 core (measured best): BK=64, A+B tiles via global_load_lds (16B/lane,
// linear LDS), single-buffer 2-barrier loop, 128x128 tile, 2x2 waves, 4x4 acc.
// XCD-chunked bijective block swizzle.
// MODE 0 (layers 1-2): N=512 = [feat 256 -> Fb bf16 | residual 256 -> Rb bf16].
// MODE 1 (layer 3):    N=640 = [feat 512 -> F8 fp8-packed | out 121(pad128) fp32].
// al4 planes: [als0 | ald0 | als1 | ald1], each N4 floats. MODE0 writes half 0
// only; MODE1 writes both halves.
template<int MODE>
__global__ __launch_bounds__(256) void mfma_gemm_fused(const short* __restrict__ A,
                                                       const short* __restrict__ Bt,
                                                       const float* __restrict__ bias,
                                                       const float* __restrict__ asv,
                                                       const float* __restrict__ adv,
                                                       unsigned short* __restrict__ Fb,
                                                       unsigned short* __restrict__ Rb,
                                                       unsigned int* __restrict__ F8,
                                                       float* __restrict__ out,
                                                       float* __restrict__ al4,
                                                       int Kp) {
    const int NW  = MODE ? 512 : 256;
    const int NCB = MODE ? 5 : 4;                     // col blocks
    __shared__ __align__(16) short AsBs[16384];       // As = [0,8192), Bs = [8192,16384)
    __shared__ __align__(16) unsigned short Cs[2][32][132];
    short* As = AsBs;
    short* Bs = AsBs + 8192;

    const int tid = threadIdx.x;
    const int l   = tid & 63;
    const int w   = tid >> 6;
    const int wm  = w >> 1, wn = w & 1;
    const int lrow = l & 15;
    const int lq   = l >> 4;

    // XCD-chunked bijective remap (m204)
    const int T = NCB * 313;
    const int flat = blockIdx.y * NCB + blockIdx.x;
    const int q8 = T >> 3, r8 = T & 7;
    const int xcd = flat & 7, sidx = flat >> 3;
    const int wg = (xcd < r8 ? xcd * (q8 + 1) : r8 * (q8 + 1) + (xcd - r8) * q8) + sidx;
    const int row0 = (wg / NCB) * 128;
    const int col0 = (wg % NCB) * 128;

    float4v acc[4][4] = {};

    // global_load_lds layout: load j, thread t -> LDS elems j*2048 + t*8
    //  == row-major [128][64]: r = j*32 + (t>>3), k = (t&7)*8
    const int lr_ld = tid >> 3;
    const int lk_ld = (tid & 7) * 8;
    const int nk = Kp >> 6;
    for (int t = 0; t < nk; ++t) {
        const int k0 = t << 6;
        if (t) __syncthreads();                       // all waves done reading LDS
        const size_t abase = (size_t)(row0 + lr_ld) * Kp + k0 + lk_ld;
        const size_t bbase = (size_t)(col0 + lr_ld) * Kp + k0 + lk_ld;
        #pragma unroll
        for (int j = 0; j < 4; ++j) {
            gl2lds16(&A[abase + (size_t)j * 32 * Kp],  &As[j * 2048 + tid * 8]);
            gl2lds16(&Bt[bbase + (size_t)j * 32 * Kp], &Bs[j * 2048 + tid * 8]);
        }
        __syncthreads();                              // drains vmcnt -> LDS ready
        #pragma unroll
        for (int ks = 0; ks < 2; ++ks) {
            short8 aF[4], bF[4];
            #pragma unroll
            for (int rt = 0; rt < 4; ++rt)
                aF[rt] = *(const short8*)&As[(wm * 64 + rt * 16 + lrow) * 64 + ks * 32 + lq * 8];
            #pragma unroll
            for (int ct = 0; ct < 4; ++ct)
                bF[ct] = *(const short8*)&Bs[(wn * 64 + ct * 16 + lrow) * 64 + ks * 32 + lq * 8];
            #pragma unroll
            for (int rt = 0; rt < 4; ++rt)
                #pragma unroll
                for (int ct = 0; ct < 4; ++ct)
                    acc[rt][ct] = __builtin_amdgcn_mfma_f32_16x16x32_bf16(aF[rt], bF[ct],
                                                                          acc[rt][ct], 0, 0, 0);
        }
    }

    const int colbase = col0 + wn * 64;           // this wave's 64-col span start
    const bool isW = colbase < NW;

    // ---- al_s / al_d reduction (W-part only; plain stores, no atomics)
    if (isW) {
        const int head = (colbase * NHEAD) / NW;
        const int half = MODE ? ((colbase >> 6) & 1) : 0;
        float* als_o = al4 + (half ? 2 * N4 : 0);
        float* ald_o = als_o + N4;
        float as_c[4], ad_c[4];
        #pragma unroll
        for (int ct = 0; ct < 4; ++ct) {
            int col = colbase + ct * 16 + lrow;
            as_c[ct] = asv[col];
            ad_c[ct] = adv[col];
        }
        #pragma unroll
        for (int rt = 0; rt < 4; ++rt) {
            #pragma unroll
            for (int i = 0; i < 4; ++i) {
                int r = row0 + wm * 64 + rt * 16 + lq * 4 + i;
                float fs = 0.f, fd = 0.f;
                #pragma unroll
                for (int ct = 0; ct < 4; ++ct) {
                    float v = acc[rt][ct][i];
                    fs += v * as_c[ct];
                    fd += v * ad_c[ct];
                }
                #pragma unroll
                for (int o2 = 8; o2; o2 >>= 1) {
                    fs += __shfl_xor(fs, o2, 16);
                    fd += __shfl_xor(fd, o2, 16);
                }
                if (lrow == 0 && r < NNODES) {
                    als_o[r * 4 + head] = fs;
                    ald_o[r * 4 + head] = fd;
                }
            }
        }
    }

    // ---- stores
    const int rp = tid >> 2, g2 = rp >> 5, rr = rp & 31, qq = tid & 3;

    if (MODE == 1 && col0 >= 512) {
        // fp32 out block (121 real cols): stage 32-row slabs in LDS, write
        // 484B-contiguous rows (full-line writes, no RMW inflation)
        float* Ls = (float*)AsBs;                 // [32][132] fp32 = 16.9KB
        #pragma unroll
        for (int p = 0; p < 4; ++p) {
            __syncthreads();                      // Ls free (aliases As/Bs)
            if (wm == (p >> 1)) {
                const int rt0 = (p & 1) * 2;
                #pragma unroll
                for (int rt2 = 0; rt2 < 2; ++rt2) {
                    int rt = rt0 + rt2;
                    #pragma unroll
                    for (int ct = 0; ct < 4; ++ct) {
                        int cl = wn * 64 + ct * 16 + lrow;
                        #pragma unroll
                        for (int i = 0; i < 4; ++i) {
                            int lr = rt2 * 16 + lq * 4 + i;
                            Ls[lr * 132 + cl] = acc[rt][ct][i];
                        }
                    }
                }
            }
            __syncthreads();
            #pragma unroll
            for (int it = 0; it < 16; ++it) {     // 32 rows x 128 cols / 256 thr
                int idx = it * 256 + tid;
                int r = idx >> 7, c = idx & 127;
                int grow = row0 + p * 32 + r;
                if (c < 121 && grow < NNODES)
                    out[(size_t)grow * 121 + c] = Ls[r * 132 + c] + bias[c];
            }
        }
        return;
    }

    if (MODE == 1) {
        // feat block -> F8 directly (bf16 round then fp8 pack)
        #pragma unroll
        for (int p = 0; p < 2; ++p) {
            if (p) __syncthreads();
            #pragma unroll
            for (int rt2 = 0; rt2 < 2; ++rt2) {
                int rt = p * 2 + rt2;
                #pragma unroll
                for (int ct = 0; ct < 4; ++ct) {
                    int cl = wn * 64 + ct * 16 + lrow;
                    #pragma unroll
                    for (int i = 0; i < 4; ++i) {
                        int lr = rt2 * 16 + lq * 4 + i;
                        Cs[wm][lr][cl] = f2bf(acc[rt][ct][i]);
                    }
                }
            }
            __syncthreads();
            int grow = row0 + g2 * 64 + p * 32 + rr;
            if (grow < NNODES) {
                #pragma unroll
                for (int k = 0; k < 4; ++k) {
                    ushort8v v = *(const ushort8v*)&Cs[g2][rr][qq * 32 + 8 * k];
                    int u0 = 0, u1 = 0;
                    u0 = __builtin_amdgcn_cvt_pk_fp8_f32(bf2f(v[0]), bf2f(v[1]), u0, false);
                    u0 = __builtin_amdgcn_cvt_pk_fp8_f32(bf2f(v[2]), bf2f(v[3]), u0, true);
                    u1 = __builtin_amdgcn_cvt_pk_fp8_f32(bf2f(v[4]), bf2f(v[5]), u1, false);
                    u1 = __builtin_amdgcn_cvt_pk_fp8_f32(bf2f(v[6]), bf2f(v[7]), u1, true);
                    uint2v wv; wv.x = (unsigned)u0; wv.y = (unsigned)u1;
                    *(uint2v*)&F8[(size_t)grow * 128 + (col0 >> 2) + qq * 8 + 2 * k] = wv;
                }
            }
        }
        return;
    }

    // MODE 0: bf16 destination (block-uniform)
    const bool isRb = col0 >= 256;
    unsigned short* dest = isRb ? Rb : Fb;
    const int cold = isRb ? col0 - 256 : col0;
    float badd[4] = {0.f, 0.f, 0.f, 0.f};
    if (isRb) {
        #pragma unroll
        for (int ct = 0; ct < 4; ++ct)
            badd[ct] = bias[col0 - 256 + wn * 64 + ct * 16 + lrow];
    }

    #pragma unroll
    for (int p = 0; p < 2; ++p) {
        if (p) __syncthreads();
        #pragma unroll
        for (int rt2 = 0; rt2 < 2; ++rt2) {
            int rt = p * 2 + rt2;
            #pragma unroll
            for (int ct = 0; ct < 4; ++ct) {
                int cl = wn * 64 + ct * 16 + lrow;
                #pragma unroll
                for (int i = 0; i < 4; ++i) {
                    int lr = rt2 * 16 + lq * 4 + i;
                    Cs[wm][lr][cl] = f2bf(acc[rt][ct][i] + badd[ct]);
                }
            }
        }
        __syncthreads();
        int grow = row0 + g2 * 64 + p * 32 + rr;
        if (grow < NNODES) {
            #pragma unroll
            for (int k = 0; k < 4; ++k) {
                ushort8v v = *(const ushort8v*)&Cs[g2][rr][qq * 32 + 8 * k];
                *(ushort8v*)&dest[(size_t)grow * 256 + cold + qq * 32 + 8 * k] = v;
            }
        }
    }
}

// --------------------------------------------------- attn layers 1-2 (C=64, concat)
// wave per node; half-wave (32 lanes) per edge, 2 edges/iter; lane = 8 ch (16B).
// 3-stage pipeline: csr[j+4] and feat[src[j+2]] in flight while edge j is FMA'd.
__global__ __launch_bounds__(256) void attn64_kernel(const unsigned short* __restrict__ featb,
                                                     const float* __restrict__ al4,
                                                     const int* __restrict__ offs,
                                                     const int* __restrict__ csr,
                                                     const float* __restrict__ p4,
                                                     const unsigned short* __restrict__ Rb,
                                                     unsigned short* __restrict__ outb) {
    int n = blockIdx.x * 4 + (threadIdx.x >> 6);
    int l = threadIdx.x & 63;
    int half = l >> 5, li = l & 31;
    int h = li >> 3;                         // 8 lanes/head, 8 ch/lane
    int beg = n ? offs[n - 1] : 0;
    int end = offs[n];

    float a[8] = {};
    float s = 0.f;

    int j = beg + half;
    int sn_n = 0;
    ushort8v u_c = {};
    float p_c = 0.f;
    if (j < end) {
        int sn_c = csr[j];
        u_c = *(const ushort8v*)&featb[(size_t)sn_c * 256 + 8 * li];
        p_c = p4[(size_t)j * 4 + h];
    }
    if (j + 2 < end) sn_n = csr[j + 2];

    for (; j < end; j += 2) {
        int j2 = j + 2;
        int sn_nn = (j2 + 2 < end) ? csr[j2 + 2] : 0;
        ushort8v u_n = *(const ushort8v*)&featb[(size_t)sn_n * 256 + 8 * li];
        float p_n = p4[(size_t)j2 * 4 + h];            // p4 carve padded for OOB
        s += p_c;
        #pragma unroll
        for (int i = 0; i < 8; ++i) a[i] += p_c * bf2f(u_c[i]);
        u_c = u_n; p_c = p_n; sn_n = sn_nn;
    }
    s += __shfl_xor(s, 32, 64);
    #pragma unroll
    for (int i = 0; i < 8; ++i) a[i] += __shfl_xor(a[i], 32, 64);

    // self-loop
    float p0 = __expf(lrelu(al4[n * 4 + h] + al4[N4 + n * 4 + h]));
    s += p0;
    {
        ushort8v f = *(const ushort8v*)&featb[(size_t)n * 256 + 8 * li];
        #pragma unroll
        for (int i = 0; i < 8; ++i) a[i] += p0 * bf2f(f[i]);
    }
    if (half == 0) {
        float inv = 1.f / s;
        ushort8v r = *(const ushort8v*)&Rb[(size_t)n * 256 + 8 * li];
        ushort8v o;
        #pragma unroll
        for (int i = 0; i < 8; ++i) o[i] = f2bf(fmaxf(bf2f(r[i]) + a[i] * inv, 0.f));
        *(ushort8v*)&outb[(size_t)n * 256 + 8 * li] = o;
    }
}

// --------------------------------------------------- attn layer 3 (fp8 feat, mean)
// wave per node; half-wave per edge (16B = 16 fp8/lane); HW fp8->f32 decode.
// Same 3-stage pipeline as attn64.
__global__ __launch_bounds__(256) void attn121_kernel(const unsigned int* __restrict__ F8,
                                                      const float* __restrict__ al4,
                                                      const int* __restrict__ offs,
                                                      const int* __restrict__ csr,
                                                      const float* __restrict__ p4,
                                                      float* __restrict__ out) {
    int n = blockIdx.x * 4 + (threadIdx.x >> 6);
    int l = threadIdx.x & 63;
    int half = l >> 5, li = l & 31;
    int h = li >> 3;                         // 8 lanes/head, 16 ch/lane (128-pad head)
    int beg = n ? offs[n - 1] : 0;
    int end = offs[n];

    float a[16] = {};
    float s = 0.f;

    int j = beg + half;
    int sn_n = 0;
    uint4v u_c = {};
    float p_c = 0.f;
    if (j < end) {
        int sn_c = csr[j];
        u_c = *(const uint4v*)&F8[(size_t)sn_c * 128 + 4 * li];
        p_c = p4[(size_t)j * 4 + h];
    }
    if (j + 2 < end) sn_n = csr[j + 2];

    for (; j < end; j += 2) {
        int j2 = j + 2;
        int sn_nn = (j2 + 2 < end) ? csr[j2 + 2] : 0;
        uint4v u_n = *(const uint4v*)&F8[(size_t)sn_n * 128 + 4 * li];
        float p_n = p4[(size_t)j2 * 4 + h];            // p4 carve padded for OOB
        s += p_c;
        #pragma unroll
        for (int k = 0; k < 4; ++k) {
            float2v lo = __builtin_amdgcn_cvt_pk_f32_fp8(u_c[k], false);
            float2v hi = __builtin_amdgcn_cvt_pk_f32_fp8(u_c[k], true);
            a[4 * k + 0] += p_c * lo.x; a[4 * k + 1] += p_c * lo.y;
            a[4 * k + 2] += p_c * hi.x; a[4 * k + 3] += p_c * hi.y;
        }
        u_c = u_n; p_c = p_n; sn_n = sn_nn;
    }
    s += __shfl_xor(s, 32, 64);
    #pragma unroll
    for (int i = 0; i < 16; ++i) a[i] += __shfl_xor(a[i], 32, 64);

    // self-loop
    float p0 = __expf(lrelu(al4[n * 4 + h] + al4[2 * N4 + n * 4 + h]
                            + al4[N4 + n * 4 + h] + al4[3 * N4 + n * 4 + h]));
    s += p0;
    {
        uint4v u = *(const uint4v*)&F8[(size_t)n * 128 + 4 * li];
        #pragma unroll
        for (int k = 0; k < 4; ++k) {
            float2v lo = __builtin_amdgcn_cvt_pk_f32_fp8(u[k], false);
            float2v hi = __builtin_amdgcn_cvt_pk_f32_fp8(u[k], true);
            a[4 * k + 0] += p0 * lo.x; a[4 * k + 1] += p0 * lo.y;
            a[4 * k + 2] += p0 * hi.x; a[4 * k + 3] += p0 * hi.y;
        }
    }
    float inv = 0.25f / s;                 // mean over heads
    #pragma unroll
    for (int i = 0; i < 16; ++i) {
        a[i] *= inv;
        a[i] += __shfl_xor(a[i], 8, 64);   // sum 4 head groups (lanes li^8, li^16)
        a[i] += __shfl_xor(a[i], 16, 64);
    }
    if (l < 8) {                           // half 0, head 0 lanes hold channel sums
        #pragma unroll
        for (int i = 0; i < 16; ++i) {
            int c = 16 * l + i;
            if (c < 121) out[(size_t)n * 121 + c] += a[i];
        }
    }
}

// ---------------------------------------------------------------- launch
extern "C" void kernel_launch(void* const* d_in, const int* in_sizes, int n_in,
                              void* d_out, int out_size, void* d_ws, size_t ws_size,
                              hipStream_t stream) {
    const float* x   = (const float*)d_in[0];
    const int* ei    = (const int*)d_in[1];
    const float* W1  = (const float*)d_in[2];
    const float* a1s = (const float*)d_in[3];
    const float* a1d = (const float*)d_in[4];
    const float* Wr1 = (const float*)d_in[5];
    const float* b1  = (const float*)d_in[6];
    const float* W2  = (const float*)d_in[7];
    const float* a2s = (const float*)d_in[8];
    const float* a2d = (const float*)d_in[9];
    const float* Wr2 = (const float*)d_in[10];
    const float* b2  = (const float*)d_in[11];
    const float* W3  = (const float*)d_in[12];
    const float* a3s = (const float*)d_in[13];
    const float* a3d = (const float*)d_in[14];
    const float* Wr3 = (const float*)d_in[15];
    const float* b3  = (const float*)d_in[16];
    float* out = (float*)d_out;

    const int* e_src = ei;
    const int* e_dst = ei + NEDGES;

    char* ws = (char*)d_ws;
    size_t off = 0;
    auto carve = [&](size_t bytes) { void* p = ws + off; off += (bytes + 255) & ~255ull; return p; };
    unsigned short* Fb = (unsigned short*)carve((size_t)MPAD * 256 * 2);
    unsigned short* Rb = (unsigned short*)carve((size_t)MPAD * 256 * 2);
    unsigned short* Hb = (unsigned short*)carve((size_t)MPAD * 256 * 2);
    unsigned int* F8 = (unsigned int*)carve((size_t)NNODES * 128 * 4);
    short* xb   = (short*)carve((size_t)MPAD * 64 * 2);
    short* wc1  = (short*)carve((size_t)512 * 64 * 2);
    short* wc2  = (short*)carve((size_t)512 * 256 * 2);
    short* wc3  = (short*)carve((size_t)640 * 256 * 2);
    float* a3sp = (float*)carve(512 * 4);
    float* a3dp = (float*)carve(512 * 4);
    float* al4  = (float*)carve((size_t)4 * N4 * 4);   // [als0|ald0|als1|ald1]
    float* p4   = (float*)carve(((size_t)NEDGES * 4 + 64) * 4);  // +pad for pipeline OOB
    int* csr_src = (int*)carve((size_t)NEDGES * 4);
    int* csr_dst = (int*)carve((size_t)NEDGES * 4);
    int* offsets = (int*)carve(((size_t)NNODES + 4) * 4);
    int* counts  = (int*)carve((size_t)NNODES * 4);
    int* partials = (int*)carve(256 * 4);
    int* pexcl    = (int*)carve(256 * 4);

    const int EB = (NEDGES + 255) / 256;
    dim3 blk(256);

    // conversions (3 launches)
    convert_x<<<(MPAD * 64 + 255) / 256, blk, 0, stream>>>(x, xb);
    convert_pack1<<<(163840 + 255) / 256, blk, 0, stream>>>(W1, Wr1, W2, Wr2, wc1, wc2);
    convert_pack2<<<(164864 + 255) / 256, blk, 0, stream>>>(W3, Wr3, a3s, a3d, wc3, a3sp, a3dp);

    // CSR by dst (parallel scan; scatter mutates offsets into end-positions)
    hipMemsetAsync(counts, 0, NNODES * 4, stream);
    hist_kernel<<<EB, blk, 0, stream>>>(e_dst, counts, NEDGES);
    scan_local<<<SCANB, blk, 0, stream>>>(counts, offsets, partials);
    scan_partials<<<1, blk, 0, stream>>>(partials, pexcl);
    scan_carry<<<SCANB, blk, 0, stream>>>(offsets, pexcl);
    scatter_kernel<<<EB, blk, 0, stream>>>(e_src, e_dst, offsets, csr_src, csr_dst, NEDGES);

    // ---- layer 1 (K=64)
    mfma_gemm_fused<0><<<dim3(4, 313), blk, 0, stream>>>(xb, wc1, b1, a1s, a1d,
                                                         Fb, Rb, nullptr, nullptr, al4, 64);
    edge_p<0><<<EB, blk, 0, stream>>>(al4, csr_src, csr_dst, p4, NEDGES);
    attn64_kernel<<<NNODES / 4, blk, 0, stream>>>(Fb, al4, offsets, csr_src, p4, Rb, Hb);

    // ---- layer 2 (K=256)
    mfma_gemm_fused<0><<<dim3(4, 313), blk, 0, stream>>>((short*)Hb, wc2, b2, a2s, a2d,
                                                         Fb, Rb, nullptr, nullptr, al4, 256);
    edge_p<0><<<EB, blk, 0, stream>>>(al4, csr_src, csr_dst, p4, NEDGES);
    attn64_kernel<<<NNODES / 4, blk, 0, stream>>>(Fb, al4, offsets, csr_src, p4, Rb, Hb);

    // ---- layer 3 (K=256, N=640): feat -> F8 fused, residual+bias -> out
    mfma_gemm_fused<1><<<dim3(5, 313), blk, 0, stream>>>((short*)Hb, wc3, b3, a3sp, a3dp,
                                                         nullptr, nullptr, F8, out, al4, 256);
    edge_p<1><<<EB, blk, 0, stream>>>(al4, csr_src, csr_dst, p4, NEDGES);
    attn121_kernel<<<NNODES / 4, blk, 0, stream>>>(F8, al4, offsets, csr_src, p4, out);
}

// Round 6
// 392.276 us; speedup vs baseline: 1.0364x; 1.0364x over previous
//
#include <hip/hip_runtime.h>
#include <hip/hip_bf16.h>

// GAT 3-layer: N=40000, E=400000 (+self-loops), H=4, HID=64, NCLS=121, F_IN=50.
// Round 16: re-fuse + occupancy. (1) edge_p folded back into attn kernels (the
// round-15 split cost 22us of dispatch+p4 traffic for a 2us gain) BUT the
// 3-stage software pipeline is kept and extended: csr[j+4], feat/F8[src[j+2]]
// AND al4[src[j+2]] all in flight while edge j is FMA'd -> exp off the critical
// path without a separate pass. (2) al_combine pre-sums layer-3's plane pairs so
// attn121's loop needs one scalar gather per edge (same as attn64). (3) GEMM
// epilogue LDS (Cs/Ls) now ALIASES As/Bs (barrier-guarded) -> LDS 49.6->32.8KB
// -> 4-5 blocks/CU (was 3): more cross-block overlap for the latency-bound
// stage drains. GEMM core + F8 epilogue fusion + XCD swizzle unchanged.

#define NNODES 40000
#define MPAD   40064    // 313 * 128
#define NEDGES 400000
#define FIN    50
#define NHEAD  4
#define SCANB  157      // ceil(40000/256)
#define N4     160000   // NNODES * NHEAD

typedef __attribute__((ext_vector_type(8))) short short8;
typedef __attribute__((ext_vector_type(4))) float float4v;
typedef __attribute__((ext_vector_type(2))) float float2v;
typedef __attribute__((ext_vector_type(4))) unsigned short ushort4v;
typedef __attribute__((ext_vector_type(8))) unsigned short ushort8v;
typedef __attribute__((ext_vector_type(2))) unsigned int uint2v;
typedef __attribute__((ext_vector_type(4))) unsigned int uint4v;

__device__ inline unsigned short f2bf(float f) {   // round-to-nearest-even bf16
    union { float f; unsigned u; } v; v.f = f;
    unsigned r = v.u + 0x7fff + ((v.u >> 16) & 1);
    return (unsigned short)(r >> 16);
}
__device__ inline float bf2f(unsigned short u) {
    union { unsigned u; float f; } v; v.u = ((unsigned)u) << 16; return v.f;
}
__device__ inline float lrelu(float x) { return x >= 0.f ? x : 0.2f * x; }

// async global->LDS, 16B per lane, wave-uniform LDS base + lane*16 (linear dest)
typedef __attribute__((address_space(3))) unsigned int lds_u32;
typedef __attribute__((address_space(1))) const unsigned int glb_u32;
__device__ __forceinline__ void gl2lds16(const short* g, short* l) {
    __builtin_amdgcn_global_load_lds((glb_u32*)g, (lds_u32*)l, 16, 0, 0);
}

// ---------------------------------------------------------------- CSR build
__global__ void hist_kernel(const int* __restrict__ dst, int* __restrict__ counts, int E) {
    int i = blockIdx.x * blockDim.x + threadIdx.x;
    if (i < E) atomicAdd(&counts[dst[i]], 1);
}

__global__ __launch_bounds__(256) void scan_local(const int* __restrict__ counts,
                                                  int* __restrict__ offsets,
                                                  int* __restrict__ partials) {
    __shared__ int sh[256];
    int b = blockIdx.x, t = threadIdx.x, i = b * 256 + t;
    int v = (i < NNODES) ? counts[i] : 0;
    sh[t] = v;
    __syncthreads();
    #pragma unroll
    for (int off = 1; off < 256; off <<= 1) {
        int u = (t >= off) ? sh[t - off] : 0;
        __syncthreads();
        sh[t] += u;
        __syncthreads();
    }
    if (i < NNODES) offsets[i] = sh[t] - v;     // local exclusive
    if (t == 255) partials[b] = sh[255];
}

__global__ __launch_bounds__(256) void scan_partials(int* __restrict__ partials,
                                                     int* __restrict__ pexcl) {
    __shared__ int sh[256];
    int t = threadIdx.x;
    int v = (t < SCANB) ? partials[t] : 0;
    sh[t] = v;
    __syncthreads();
    #pragma unroll
    for (int off = 1; off < 256; off <<= 1) {
        int u = (t >= off) ? sh[t - off] : 0;
        __syncthreads();
        sh[t] += u;
        __syncthreads();
    }
    pexcl[t] = sh[t] - v;
}

__global__ __launch_bounds__(256) void scan_carry(int* __restrict__ offsets,
                                                  const int* __restrict__ pexcl) {
    int b = blockIdx.x, i = b * 256 + threadIdx.x;
    if (i < NNODES) offsets[i] += pexcl[b];
}

// mutates offsets: after this, offsets[d] = end(d); beg(d) = offsets[d-1] (0 for d=0)
__global__ void scatter_kernel(const int* __restrict__ src, const int* __restrict__ dst,
                               int* __restrict__ offsets,
                               int* __restrict__ csr_src, int E) {
    int i = blockIdx.x * blockDim.x + threadIdx.x;
    if (i < E) {
        int d = dst[i];
        int pos = atomicAdd(&offsets[d], 1);
        csr_src[pos] = src[i];
    }
}

// layer-3 logit planes: als_comb (plane 2) += als0 (plane 0); ald_comb (3) += ald0 (1)
__global__ void al_combine(float* __restrict__ al4) {
    int i = blockIdx.x * blockDim.x + threadIdx.x;   // over 80000 float4s
    if (i >= 80000) return;
    float4v* dst; const float4v* src;
    if (i < 40000) { dst = (float4v*)&al4[2 * N4] + i;            src = (const float4v*)&al4[0] + i; }
    else           { dst = (float4v*)&al4[3 * N4] + (i - 40000);  src = (const float4v*)&al4[N4] + (i - 40000); }
    float4v d = *dst, s0 = *src;
    d.x += s0.x; d.y += s0.y; d.z += s0.z; d.w += s0.w;
    *dst = d;
}

// ---------------------------------------------------------------- converts
__global__ void convert_x(const float* __restrict__ x, short* __restrict__ xb) {
    int i = blockIdx.x * blockDim.x + threadIdx.x;   // over MPAD*64
    if (i >= MPAD * 64) return;
    int r = i >> 6, k = i & 63;
    float v = (r < NNODES && k < FIN) ? x[r * FIN + k] : 0.f;
    xb[i] = f2bf(v);
}

// fused: wc1 = [W1^T|Wr1^T] (Kpad 64), wc2 = [W2^T|Wr2^T] (Kpad 256)
__global__ void convert_pack1(const float* __restrict__ W1, const float* __restrict__ Wr1,
                              const float* __restrict__ W2, const float* __restrict__ Wr2,
                              short* __restrict__ wc1, short* __restrict__ wc2) {
    int i = blockIdx.x * blockDim.x + threadIdx.x;
    if (i < 32768) {
        const float* W = (i < 16384) ? W1 : Wr1;
        int j = i & 16383;
        int n = j >> 6, k = j & 63;
        wc1[i] = f2bf((k < FIN) ? W[k * 256 + n] : 0.f);
    } else if (i < 163840) {
        int j = (i - 32768) & 65535;
        const float* W = (i < 98304) ? W2 : Wr2;
        int n = j >> 8, k = j & 255;
        wc2[(i - 32768)] = f2bf(W[k * 256 + n]);
    }
}

// fused: wc3 rows 0-511 = W3^T head-padded, rows 512-639 = Wr3^T; a3 pads [4][128]
__global__ void convert_pack2(const float* __restrict__ W3, const float* __restrict__ Wr3,
                              const float* __restrict__ a3s, const float* __restrict__ a3d,
                              short* __restrict__ wc3,
                              float* __restrict__ a3sp, float* __restrict__ a3dp) {
    int i = blockIdx.x * blockDim.x + threadIdx.x;
    if (i < 131072) {
        int j = i >> 8, k = i & 255;
        int h = j >> 7, c = j & 127;
        wc3[i] = f2bf((c < 121) ? W3[k * 484 + h * 121 + c] : 0.f);
    } else if (i < 163840) {
        int j = i - 131072;
        int n = j >> 8, k = j & 255;
        wc3[131072 + j] = f2bf((n < 121) ? Wr3[k * 121 + n] : 0.f);
    } else if (i < 164864) {
        int j = i - 163840;
        int which = j >> 9; int jj = j & 511;
        int h = jj >> 7, c = jj & 127;
        float v = (c < 121) ? (which ? a3d[h * 121 + c] : a3s[h * 121 + c]) : 0.f;
        (which ? a3dp : a3sp)[jj] = v;
    }
}

// ---------------------------------------------------------------- fused MFMA GEMM
// Round-1 core: BK=64, A+B via global_load_lds (16B/lane, linear LDS), 2-barrier
// loop, 128x128 tile, 2x2 waves, 4x4 acc. XCD-chunked bijective block swizzle.
// Epilogue Cs (bf16) / Ls (fp32) ALIAS the As/Bs block (barrier-guarded) ->
// LDS 32.8KB -> 4-5 blocks/CU.
// MODE 0 (layers 1-2): N=512 = [feat 256 -> Fb bf16 | residual 256 -> Rb bf16].
// MODE 1 (layer 3):    N=640 = [feat 512 -> F8 fp8-packed | out 121(pad128) fp32].
// al4 planes: [als0 | ald0 | als1 | ald1], each N4 floats.
template<int MODE>
__global__ __launch_bounds__(256) void mfma_gemm_fused(const short* __restrict__ A,
                                                       const short* __restrict__ Bt,
                                                       const float* __restrict__ bias,
                                                       const float* __restrict__ asv,
                                                       const float* __restrict__ adv,
                                                       unsigned short* __restrict__ Fb,
                                                       unsigned short* __restrict__ Rb,
                                                       unsigned int* __restrict__ F8,
                                                       float* __restrict__ out,
                                                       float* __restrict__ al4,
                                                       int Kp) {
    const int NW  = MODE ? 512 : 256;
    const int NCB = MODE ? 5 : 4;                     // col blocks
    __shared__ __align__(16) char smem[32768];        // As | Bs ; epilogue aliases
    short* As = (short*)smem;
    short* Bs = (short*)(smem + 16384);
    auto Cs = (unsigned short (*)[32][132])smem;      // [2][32][132] bf16 epilogue
    float* Ls = (float*)smem;                         // [32][132] fp32 epilogue

    const int tid = threadIdx.x;
    const int l   = tid & 63;
    const int w   = tid >> 6;
    const int wm  = w >> 1, wn = w & 1;
    const int lrow = l & 15;
    const int lq   = l >> 4;

    // XCD-chunked bijective remap (m204)
    const int T = NCB * 313;
    const int flat = blockIdx.y * NCB + blockIdx.x;
    const int q8 = T >> 3, r8 = T & 7;
    const int xcd = flat & 7, sidx = flat >> 3;
    const int wg = (xcd < r8 ? xcd * (q8 + 1) : r8 * (q8 + 1) + (xcd - r8) * q8) + sidx;
    const int row0 = (wg / NCB) * 128;
    const int col0 = (wg % NCB) * 128;

    float4v acc[4][4] = {};

    // global_load_lds layout: load j, thread t -> LDS elems j*2048 + t*8
    //  == row-major [128][64]: r = j*32 + (t>>3), k = (t&7)*8
    const int lr_ld = tid >> 3;
    const int lk_ld = (tid & 7) * 8;
    const int nk = Kp >> 6;
    for (int t = 0; t < nk; ++t) {
        const int k0 = t << 6;
        if (t) __syncthreads();                       // all waves done reading LDS
        const size_t abase = (size_t)(row0 + lr_ld) * Kp + k0 + lk_ld;
        const size_t bbase = (size_t)(col0 + lr_ld) * Kp + k0 + lk_ld;
        #pragma unroll
        for (int j = 0; j < 4; ++j) {
            gl2lds16(&A[abase + (size_t)j * 32 * Kp],  &As[j * 2048 + tid * 8]);
            gl2lds16(&Bt[bbase + (size_t)j * 32 * Kp], &Bs[j * 2048 + tid * 8]);
        }
        __syncthreads();                              // drains vmcnt -> LDS ready
        #pragma unroll
        for (int ks = 0; ks < 2; ++ks) {
            short8 aF[4], bF[4];
            #pragma unroll
            for (int rt = 0; rt < 4; ++rt)
                aF[rt] = *(const short8*)&As[(wm * 64 + rt * 16 + lrow) * 64 + ks * 32 + lq * 8];
            #pragma unroll
            for (int ct = 0; ct < 4; ++ct)
                bF[ct] = *(const short8*)&Bs[(wn * 64 + ct * 16 + lrow) * 64 + ks * 32 + lq * 8];
            #pragma unroll
            for (int rt = 0; rt < 4; ++rt)
                #pragma unroll
                for (int ct = 0; ct < 4; ++ct)
                    acc[rt][ct] = __builtin_amdgcn_mfma_f32_16x16x32_bf16(aF[rt], bF[ct],
                                                                          acc[rt][ct], 0, 0, 0);
        }
    }

    const int colbase = col0 + wn * 64;           // this wave's 64-col span start
    const bool isW = colbase < NW;

    // ---- al_s / al_d reduction (W-part only; plain stores, no atomics)
    if (isW) {
        const int head = (colbase * NHEAD) / NW;
        const int half = MODE ? ((colbase >> 6) & 1) : 0;
        float* als_o = al4 + (half ? 2 * N4 : 0);
        float* ald_o = als_o + N4;
        float as_c[4], ad_c[4];
        #pragma unroll
        for (int ct = 0; ct < 4; ++ct) {
            int col = colbase + ct * 16 + lrow;
            as_c[ct] = asv[col];
            ad_c[ct] = adv[col];
        }
        #pragma unroll
        for (int rt = 0; rt < 4; ++rt) {
            #pragma unroll
            for (int i = 0; i < 4; ++i) {
                int r = row0 + wm * 64 + rt * 16 + lq * 4 + i;
                float fs = 0.f, fd = 0.f;
                #pragma unroll
                for (int ct = 0; ct < 4; ++ct) {
                    float v = acc[rt][ct][i];
                    fs += v * as_c[ct];
                    fd += v * ad_c[ct];
                }
                #pragma unroll
                for (int o2 = 8; o2; o2 >>= 1) {
                    fs += __shfl_xor(fs, o2, 16);
                    fd += __shfl_xor(fd, o2, 16);
                }
                if (lrow == 0 && r < NNODES) {
                    als_o[r * 4 + head] = fs;
                    ald_o[r * 4 + head] = fd;
                }
            }
        }
    }

    // ---- stores
    const int rp = tid >> 2, g2 = rp >> 5, rr = rp & 31, qq = tid & 3;

    if (MODE == 1 && col0 >= 512) {
        // fp32 out block (121 real cols): stage 32-row slabs in LDS, write
        // 484B-contiguous rows (full-line writes, no RMW inflation)
        #pragma unroll
        for (int p = 0; p < 4; ++p) {
            __syncthreads();                      // Ls free (aliases As/Bs)
            if (wm == (p >> 1)) {
                const int rt0 = (p & 1) * 2;
                #pragma unroll
                for (int rt2 = 0; rt2 < 2; ++rt2) {
                    int rt = rt0 + rt2;
                    #pragma unroll
                    for (int ct = 0; ct < 4; ++ct) {
                        int cl = wn * 64 + ct * 16 + lrow;
                        #pragma unroll
                        for (int i = 0; i < 4; ++i) {
                            int lr = rt2 * 16 + lq * 4 + i;
                            Ls[lr * 132 + cl] = acc[rt][ct][i];
                        }
                    }
                }
            }
            __syncthreads();
            #pragma unroll
            for (int it = 0; it < 16; ++it) {     // 32 rows x 128 cols / 256 thr
                int idx = it * 256 + tid;
                int r = idx >> 7, c = idx & 127;
                int grow = row0 + p * 32 + r;
                if (c < 121 && grow < NNODES)
                    out[(size_t)grow * 121 + c] = Ls[r * 132 + c] + bias[c];
            }
        }
        return;
    }

    if (MODE == 1) {
        // feat block -> F8 directly (bf16 round then fp8 pack)
        #pragma unroll
        for (int p = 0; p < 2; ++p) {
            __syncthreads();                      // Cs free (aliases As/Bs)
            #pragma unroll
            for (int rt2 = 0; rt2 < 2; ++rt2) {
                int rt = p * 2 + rt2;
                #pragma unroll
                for (int ct = 0; ct < 4; ++ct) {
                    int cl = wn * 64 + ct * 16 + lrow;
                    #pragma unroll
                    for (int i = 0; i < 4; ++i) {
                        int lr = rt2 * 16 + lq * 4 + i;
                        Cs[wm][lr][cl] = f2bf(acc[rt][ct][i]);
                    }
                }
            }
            __syncthreads();
            int grow = row0 + g2 * 64 + p * 32 + rr;
            if (grow < NNODES) {
                #pragma unroll
                for (int k = 0; k < 4; ++k) {
                    ushort8v v = *(const ushort8v*)&Cs[g2][rr][qq * 32 + 8 * k];
                    int u0 = 0, u1 = 0;
                    u0 = __builtin_amdgcn_cvt_pk_fp8_f32(bf2f(v[0]), bf2f(v[1]), u0, false);
                    u0 = __builtin_amdgcn_cvt_pk_fp8_f32(bf2f(v[2]), bf2f(v[3]), u0, true);
                    u1 = __builtin_amdgcn_cvt_pk_fp8_f32(bf2f(v[4]), bf2f(v[5]), u1, false);
                    u1 = __builtin_amdgcn_cvt_pk_fp8_f32(bf2f(v[6]), bf2f(v[7]), u1, true);
                    uint2v wv; wv.x = (unsigned)u0; wv.y = (unsigned)u1;
                    *(uint2v*)&F8[(size_t)grow * 128 + (col0 >> 2) + qq * 8 + 2 * k] = wv;
                }
            }
        }
        return;
    }

    // MODE 0: bf16 destination (block-uniform)
    const bool isRb = col0 >= 256;
    unsigned short* dest = isRb ? Rb : Fb;
    const int cold = isRb ? col0 - 256 : col0;
    float badd[4] = {0.f, 0.f, 0.f, 0.f};
    if (isRb) {
        #pragma unroll
        for (int ct = 0; ct < 4; ++ct)
            badd[ct] = bias[col0 - 256 + wn * 64 + ct * 16 + lrow];
    }

    #pragma unroll
    for (int p = 0; p < 2; ++p) {
        __syncthreads();                          // Cs free (aliases As/Bs)
        #pragma unroll
        for (int rt2 = 0; rt2 < 2; ++rt2) {
            int rt = p * 2 + rt2;
            #pragma unroll
            for (int ct = 0; ct < 4; ++ct) {
                int cl = wn * 64 + ct * 16 + lrow;
                #pragma unroll
                for (int i = 0; i < 4; ++i) {
                    int lr = rt2 * 16 + lq * 4 + i;
                    Cs[wm][lr][cl] = f2bf(acc[rt][ct][i] + badd[ct]);
                }
            }
        }
        __syncthreads();
        int grow = row0 + g2 * 64 + p * 32 + rr;
        if (grow < NNODES) {
            #pragma unroll
            for (int k = 0; k < 4; ++k) {
                ushort8v v = *(const ushort8v*)&Cs[g2][rr][qq * 32 + 8 * k];
                *(ushort8v*)&dest[(size_t)grow * 256 + cold + qq * 32 + 8 * k] = v;
            }
        }
    }
}

// --------------------------------------------------- attn layers 1-2 (C=64, concat)
// wave per node; half-wave (32 lanes) per edge, 2 edges/iter; lane = 8 ch (16B).
// 3-stage pipeline: csr[j+4], feat[src[j+2]], al4[src[j+2]] in flight while edge
// j is FMA'd; exp computed on prefetched operand (off the critical path).
__global__ __launch_bounds__(256) void attn64_kernel(const unsigned short* __restrict__ featb,
                                                     const float* __restrict__ al4,
                                                     const int* __restrict__ offs,
                                                     const int* __restrict__ csr,
                                                     const unsigned short* __restrict__ Rb,
                                                     unsigned short* __restrict__ outb) {
    int n = blockIdx.x * 4 + (threadIdx.x >> 6);
    int l = threadIdx.x & 63;
    int half = l >> 5, li = l & 31;
    int h = li >> 3;                         // 8 lanes/head, 8 ch/lane
    int beg = n ? offs[n - 1] : 0;
    int end = offs[n];
    float d0 = al4[N4 + n * 4 + h];          // ald0[n,h]

    float a[8] = {};
    float s = 0.f;

    int j = beg + half;
    int sn_n = 0;
    ushort8v u_c = {};
    float al_c = 0.f;
    if (j < end) {
        int sn_c = csr[j];
        u_c = *(const ushort8v*)&featb[(size_t)sn_c * 256 + 8 * li];
        al_c = al4[sn_c * 4 + h];
    }
    if (j + 2 < end) sn_n = csr[j + 2];

    for (; j < end; j += 2) {
        int j2 = j + 2;
        int sn_nn = (j2 + 2 < end) ? csr[j2 + 2] : 0;
        ushort8v u_n = *(const ushort8v*)&featb[(size_t)sn_n * 256 + 8 * li];
        float al_n = al4[sn_n * 4 + h];
        float p_c = __expf(lrelu(al_c + d0));
        s += p_c;
        #pragma unroll
        for (int i = 0; i < 8; ++i) a[i] += p_c * bf2f(u_c[i]);
        u_c = u_n; al_c = al_n; sn_n = sn_nn;
    }
    s += __shfl_xor(s, 32, 64);
    #pragma unroll
    for (int i = 0; i < 8; ++i) a[i] += __shfl_xor(a[i], 32, 64);

    // self-loop
    float p0 = __expf(lrelu(al4[n * 4 + h] + d0));
    s += p0;
    {
        ushort8v f = *(const ushort8v*)&featb[(size_t)n * 256 + 8 * li];
        #pragma unroll
        for (int i = 0; i < 8; ++i) a[i] += p0 * bf2f(f[i]);
    }
    if (half == 0) {
        float inv = 1.f / s;
        ushort8v r = *(const ushort8v*)&Rb[(size_t)n * 256 + 8 * li];
        ushort8v o;
        #pragma unroll
        for (int i = 0; i < 8; ++i) o[i] = f2bf(fmaxf(bf2f(r[i]) + a[i] * inv, 0.f));
        *(ushort8v*)&outb[(size_t)n * 256 + 8 * li] = o;
    }
}

// --------------------------------------------------- attn layer 3 (fp8 feat, mean)
// wave per node; half-wave per edge (16B = 16 fp8/lane); HW fp8->f32 decode.
// Reads COMBINED planes (al_combine): alS = plane 2, alD = plane 3.
__global__ __launch_bounds__(256) void attn121_kernel(const unsigned int* __restrict__ F8,
                                                      const float* __restrict__ al4,
                                                      const int* __restrict__ offs,
                                                      const int* __restrict__ csr,
                                                      float* __restrict__ out) {
    int n = blockIdx.x * 4 + (threadIdx.x >> 6);
    int l = threadIdx.x & 63;
    int half = l >> 5, li = l & 31;
    int h = li >> 3;                         // 8 lanes/head, 16 ch/lane (128-pad head)
    int beg = n ? offs[n - 1] : 0;
    int end = offs[n];
    float dD = al4[3 * N4 + n * 4 + h];      // combined ald[n,h]

    float a[16] = {};
    float s = 0.f;

    int j = beg + half;
    int sn_n = 0;
    uint4v u_c = {};
    float al_c = 0.f;
    if (j < end) {
        int sn_c = csr[j];
        u_c = *(const uint4v*)&F8[(size_t)sn_c * 128 + 4 * li];
        al_c = al4[2 * N4 + sn_c * 4 + h];
    }
    if (j + 2 < end) sn_n = csr[j + 2];

    for (; j < end; j += 2) {
        int j2 = j + 2;
        int sn_nn = (j2 + 2 < end) ? csr[j2 + 2] : 0;
        uint4v u_n = *(const uint4v*)&F8[(size_t)sn_n * 128 + 4 * li];
        float al_n = al4[2 * N4 + sn_n * 4 + h];
        float p_c = __expf(lrelu(al_c + dD));
        s += p_c;
        #pragma unroll
        for (int k = 0; k < 4; ++k) {
            float2v lo = __builtin_amdgcn_cvt_pk_f32_fp8(u_c[k], false);
            float2v hi = __builtin_amdgcn_cvt_pk_f32_fp8(u_c[k], true);
            a[4 * k + 0] += p_c * lo.x; a[4 * k + 1] += p_c * lo.y;
            a[4 * k + 2] += p_c * hi.x; a[4 * k + 3] += p_c * hi.y;
        }
        u_c = u_n; al_c = al_n; sn_n = sn_nn;
    }
    s += __shfl_xor(s, 32, 64);
    #pragma unroll
    for (int i = 0; i < 16; ++i) a[i] += __shfl_xor(a[i], 32, 64);

    // self-loop
    float p0 = __expf(lrelu(al4[2 * N4 + n * 4 + h] + dD));
    s += p0;
    {
        uint4v u = *(const uint4v*)&F8[(size_t)n * 128 + 4 * li];
        #pragma unroll
        for (int k = 0; k < 4; ++k) {
            float2v lo = __builtin_amdgcn_cvt_pk_f32_fp8(u[k], false);
            float2v hi = __builtin_amdgcn_cvt_pk_f32_fp8(u[k], true);
            a[4 * k + 0] += p0 * lo.x; a[4 * k + 1] += p0 * lo.y;
            a[4 * k + 2] += p0 * hi.x; a[4 * k + 3] += p0 * hi.y;
        }
    }
    float inv = 0.25f / s;                 // mean over heads
    #pragma unroll
    for (int i = 0; i < 16; ++i) {
        a[i] *= inv;
        a[i] += __shfl_xor(a[i], 8, 64);   // sum 4 head groups (lanes li^8, li^16)
        a[i] += __shfl_xor(a[i], 16, 64);
    }
    if (l < 8) {                           // half 0, head 0 lanes hold channel sums
        #pragma unroll
        for (int i = 0; i < 16; ++i) {
            int c = 16 * l + i;
            if (c < 121) out[(size_t)n * 121 + c] += a[i];
        }
    }
}

// ---------------------------------------------------------------- launch
extern "C" void kernel_launch(void* const* d_in, const int* in_sizes, int n_in,
                              void* d_out, int out_size, void* d_ws, size_t ws_size,
                              hipStream_t stream) {
    const float* x   = (const float*)d_in[0];
    const int* ei    = (const int*)d_in[1];
    const float* W1  = (const float*)d_in[2];
    const float* a1s = (const float*)d_in[3];
    const float* a1d = (const float*)d_in[4];
    const float* Wr1 = (const float*)d_in[5];
    const float* b1  = (const float*)d_in[6];
    const float* W2  = (const float*)d_in[7];
    const float* a2s = (const float*)d_in[8];
    const float* a2d = (const float*)d_in[9];
    const float* Wr2 = (const float*)d_in[10];
    const float* b2  = (const float*)d_in[11];
    const float* W3  = (const float*)d_in[12];
    const float* a3s = (const float*)d_in[13];
    const float* a3d = (const float*)d_in[14];
    const float* Wr3 = (const float*)d_in[15];
    const float* b3  = (const float*)d_in[16];
    float* out = (float*)d_out;

    const int* e_src = ei;
    const int* e_dst = ei + NEDGES;

    char* ws = (char*)d_ws;
    size_t off = 0;
    auto carve = [&](size_t bytes) { void* p = ws + off; off += (bytes + 255) & ~255ull; return p; };
    unsigned short* Fb = (unsigned short*)carve((size_t)MPAD * 256 * 2);
    unsigned short* Rb = (unsigned short*)carve((size_t)MPAD * 256 * 2);
    unsigned short* Hb = (unsigned short*)carve((size_t)MPAD * 256 * 2);
    unsigned int* F8 = (unsigned int*)carve((size_t)NNODES * 128 * 4);
    short* xb   = (short*)carve((size_t)MPAD * 64 * 2);
    short* wc1  = (short*)carve((size_t)512 * 64 * 2);
    short* wc2  = (short*)carve((size_t)512 * 256 * 2);
    short* wc3  = (short*)carve((size_t)640 * 256 * 2);
    float* a3sp = (float*)carve(512 * 4);
    float* a3dp = (float*)carve(512 * 4);
    float* al4  = (float*)carve((size_t)4 * N4 * 4);   // [als0|ald0|alS|alD]
    int* csr_src = (int*)carve((size_t)NEDGES * 4);
    int* offsets = (int*)carve(((size_t)NNODES + 4) * 4);
    int* counts  = (int*)carve((size_t)NNODES * 4);
    int* partials = (int*)carve(256 * 4);
    int* pexcl    = (int*)carve(256 * 4);

    const int EB = (NEDGES + 255) / 256;
    dim3 blk(256);

    // conversions (3 launches)
    convert_x<<<(MPAD * 64 + 255) / 256, blk, 0, stream>>>(x, xb);
    convert_pack1<<<(163840 + 255) / 256, blk, 0, stream>>>(W1, Wr1, W2, Wr2, wc1, wc2);
    convert_pack2<<<(164864 + 255) / 256, blk, 0, stream>>>(W3, Wr3, a3s, a3d, wc3, a3sp, a3dp);

    // CSR by dst (parallel scan; scatter mutates offsets into end-positions)
    hipMemsetAsync(counts, 0, NNODES * 4, stream);
    hist_kernel<<<EB, blk, 0, stream>>>(e_dst, counts, NEDGES);
    scan_local<<<SCANB, blk, 0, stream>>>(counts, offsets, partials);
    scan_partials<<<1, blk, 0, stream>>>(partials, pexcl);
    scan_carry<<<SCANB, blk, 0, stream>>>(offsets, pexcl);
    scatter_kernel<<<EB, blk, 0, stream>>>(e_src, e_dst, offsets, csr_src, NEDGES);

    // ---- layer 1 (K=64)
    mfma_gemm_fused<0><<<dim3(4, 313), blk, 0, stream>>>(xb, wc1, b1, a1s, a1d,
                                                         Fb, Rb, nullptr, nullptr, al4, 64);
    attn64_kernel<<<NNODES / 4, blk, 0, stream>>>(Fb, al4, offsets, csr_src, Rb, Hb);

    // ---- layer 2 (K=256)
    mfma_gemm_fused<0><<<dim3(4, 313), blk, 0, stream>>>((short*)Hb, wc2, b2, a2s, a2d,
                                                         Fb, Rb, nullptr, nullptr, al4, 256);
    attn64_kernel<<<NNODES / 4, blk, 0, stream>>>(Fb, al4, offsets, csr_src, Rb, Hb);

    // ---- layer 3 (K=256, N=640): feat -> F8 fused, residual+bias -> out
    mfma_gemm_fused<1><<<dim3(5, 313), blk, 0, stream>>>((short*)Hb, wc3, b3, a3sp, a3dp,
                                                         nullptr, nullptr, F8, out, al4, 256);
    al_combine<<<313, blk, 0, stream>>>(al4);
    attn121_kernel<<<NNODES / 4, blk, 0, stream>>>(F8, al4, offsets, csr_src, out);
}

// Round 7
// 380.489 us; speedup vs baseline: 1.0686x; 1.0310x over previous
//
#include <hip/hip_runtime.h>
#include <hip/hip_bf16.h>

// GAT 3-layer: N=40000, E=400000 (+self-loops), H=4, HID=64, NCLS=121, F_IN=50.
// Round 17: consolidation. (1) GEMM epilogue reverted to the round-4 (measured
// best) layout: Cs bf16 buffer SEPARATE from As/Bs (LDS 49.6KB), if(p) barrier
// pattern; round-6's aliasing+extra barriers cost 6us and bought no occupancy.
// (2) attn64/attn121 keep the round-6 3-stage pipeline (csr[j+4], feat[j+2],
// al4[j+2] in flight; exp off the critical path) + al_combine for layer 3.
// (3) convert_x/pack1/pack2/hist merged into ONE range-split init_all dispatch
// (-3 dispatches). F8 epilogue fusion, XCD swizzle, CSR scan chain unchanged.

#define NNODES 40000
#define MPAD   40064    // 313 * 128
#define NEDGES 400000
#define FIN    50
#define NHEAD  4
#define SCANB  157      // ceil(40000/256)
#define N4     160000   // NNODES * NHEAD

typedef __attribute__((ext_vector_type(8))) short short8;
typedef __attribute__((ext_vector_type(4))) float float4v;
typedef __attribute__((ext_vector_type(2))) float float2v;
typedef __attribute__((ext_vector_type(4))) unsigned short ushort4v;
typedef __attribute__((ext_vector_type(8))) unsigned short ushort8v;
typedef __attribute__((ext_vector_type(2))) unsigned int uint2v;
typedef __attribute__((ext_vector_type(4))) unsigned int uint4v;

__device__ inline unsigned short f2bf(float f) {   // round-to-nearest-even bf16
    union { float f; unsigned u; } v; v.f = f;
    unsigned r = v.u + 0x7fff + ((v.u >> 16) & 1);
    return (unsigned short)(r >> 16);
}
__device__ inline float bf2f(unsigned short u) {
    union { unsigned u; float f; } v; v.u = ((unsigned)u) << 16; return v.f;
}
__device__ inline float lrelu(float x) { return x >= 0.f ? x : 0.2f * x; }

// async global->LDS, 16B per lane, wave-uniform LDS base + lane*16 (linear dest)
typedef __attribute__((address_space(3))) unsigned int lds_u32;
typedef __attribute__((address_space(1))) const unsigned int glb_u32;
__device__ __forceinline__ void gl2lds16(const short* g, short* l) {
    __builtin_amdgcn_global_load_lds((glb_u32*)g, (lds_u32*)l, 16, 0, 0);
}

// ---------------------------------------------------------------- init (fused)
// range-split: [0, MPAD*64) convert_x | [..+163840) pack1 | [..+164864) pack2 |
// [..+NEDGES) hist. counts must be zeroed before this kernel.
#define R0 (MPAD * 64)
#define R1 (R0 + 163840)
#define R2 (R1 + 164864)
#define R3 (R2 + NEDGES)
__global__ void init_all(const float* __restrict__ x, short* __restrict__ xb,
                         const float* __restrict__ W1, const float* __restrict__ Wr1,
                         const float* __restrict__ W2, const float* __restrict__ Wr2,
                         short* __restrict__ wc1, short* __restrict__ wc2,
                         const float* __restrict__ W3, const float* __restrict__ Wr3,
                         const float* __restrict__ a3s, const float* __restrict__ a3d,
                         short* __restrict__ wc3,
                         float* __restrict__ a3sp, float* __restrict__ a3dp,
                         const int* __restrict__ e_dst, int* __restrict__ counts) {
    int i = blockIdx.x * blockDim.x + threadIdx.x;
    if (i < R0) {
        int r = i >> 6, k = i & 63;
        float v = (r < NNODES && k < FIN) ? x[r * FIN + k] : 0.f;
        xb[i] = f2bf(v);
    } else if (i < R1) {
        int j = i - R0;
        if (j < 32768) {
            const float* W = (j < 16384) ? W1 : Wr1;
            int jj = j & 16383;
            int n = jj >> 6, k = jj & 63;
            wc1[j] = f2bf((k < FIN) ? W[k * 256 + n] : 0.f);
        } else {
            int jj = (j - 32768) & 65535;
            const float* W = (j < 98304) ? W2 : Wr2;
            int n = jj >> 8, k = jj & 255;
            wc2[j - 32768] = f2bf(W[k * 256 + n]);
        }
    } else if (i < R2) {
        int j = i - R1;
        if (j < 131072) {
            int jj = j >> 8, k = j & 255;
            int h = jj >> 7, c = jj & 127;
            wc3[j] = f2bf((c < 121) ? W3[k * 484 + h * 121 + c] : 0.f);
        } else if (j < 163840) {
            int jj = j - 131072;
            int n = jj >> 8, k = jj & 255;
            wc3[131072 + jj] = f2bf((n < 121) ? Wr3[k * 121 + n] : 0.f);
        } else {
            int jj = j - 163840;
            int which = jj >> 9; int j2 = jj & 511;
            int h = j2 >> 7, c = j2 & 127;
            float v = (c < 121) ? (which ? a3d[h * 121 + c] : a3s[h * 121 + c]) : 0.f;
            (which ? a3dp : a3sp)[j2] = v;
        }
    } else if (i < R3) {
        atomicAdd(&counts[e_dst[i - R2]], 1);
    }
}

// ---------------------------------------------------------------- CSR build
__global__ __launch_bounds__(256) void scan_local(const int* __restrict__ counts,
                                                  int* __restrict__ offsets,
                                                  int* __restrict__ partials) {
    __shared__ int sh[256];
    int b = blockIdx.x, t = threadIdx.x, i = b * 256 + t;
    int v = (i < NNODES) ? counts[i] : 0;
    sh[t] = v;
    __syncthreads();
    #pragma unroll
    for (int off = 1; off < 256; off <<= 1) {
        int u = (t >= off) ? sh[t - off] : 0;
        __syncthreads();
        sh[t] += u;
        __syncthreads();
    }
    if (i < NNODES) offsets[i] = sh[t] - v;     // local exclusive
    if (t == 255) partials[b] = sh[255];
}

__global__ __launch_bounds__(256) void scan_partials(int* __restrict__ partials,
                                                     int* __restrict__ pexcl) {
    __shared__ int sh[256];
    int t = threadIdx.x;
    int v = (t < SCANB) ? partials[t] : 0;
    sh[t] = v;
    __syncthreads();
    #pragma unroll
    for (int off = 1; off < 256; off <<= 1) {
        int u = (t >= off) ? sh[t - off] : 0;
        __syncthreads();
        sh[t] += u;
        __syncthreads();
    }
    pexcl[t] = sh[t] - v;
}

__global__ __launch_bounds__(256) void scan_carry(int* __restrict__ offsets,
                                                  const int* __restrict__ pexcl) {
    int b = blockIdx.x, i = b * 256 + threadIdx.x;
    if (i < NNODES) offsets[i] += pexcl[b];
}

// mutates offsets: after this, offsets[d] = end(d); beg(d) = offsets[d-1] (0 for d=0)
__global__ void scatter_kernel(const int* __restrict__ src, const int* __restrict__ dst,
                               int* __restrict__ offsets,
                               int* __restrict__ csr_src, int E) {
    int i = blockIdx.x * blockDim.x + threadIdx.x;
    if (i < E) {
        int d = dst[i];
        int pos = atomicAdd(&offsets[d], 1);
        csr_src[pos] = src[i];
    }
}

// layer-3 logit planes: als_comb (plane 2) += als0 (plane 0); ald_comb (3) += ald0 (1)
__global__ void al_combine(float* __restrict__ al4) {
    int i = blockIdx.x * blockDim.x + threadIdx.x;   // over 80000 float4s
    if (i >= 80000) return;
    float4v* dst; const float4v* src;
    if (i < 40000) { dst = (float4v*)&al4[2 * N4] + i;            src = (const float4v*)&al4[0] + i; }
    else           { dst = (float4v*)&al4[3 * N4] + (i - 40000);  src = (const float4v*)&al4[N4] + (i - 40000); }
    float4v d = *dst, s0 = *src;
    d.x += s0.x; d.y += s0.y; d.z += s0.z; d.w += s0.w;
    *dst = d;
}

// ---------------------------------------------------------------- fused MFMA GEMM
// Round-4 config (measured best): BK=64, A+B via global_load_lds (16B/lane,
// linear LDS), 2-barrier loop, 128x128 tile, 2x2 waves, 4x4 acc; Cs bf16 buffer
// SEPARATE (LDS 49.6KB); Ls fp32 epilogue aliases AsBs (barrier-guarded).
// XCD-chunked bijective block swizzle.
// MODE 0 (layers 1-2): N=512 = [feat 256 -> Fb bf16 | residual 256 -> Rb bf16].
// MODE 1 (layer 3):    N=640 = [feat 512 -> F8 fp8-packed | out 121(pad128) fp32].
// al4 planes: [als0 | ald0 | als1 | ald1], each N4 floats.
template<int MODE>
__global__ __launch_bounds__(256) void mfma_gemm_fused(const short* __restrict__ A,
                                                       const short* __restrict__ Bt,
                                                       const float* __restrict__ bias,
                                                       const float* __restrict__ asv,
                                                       const float* __restrict__ adv,
                                                       unsigned short* __restrict__ Fb,
                                                       unsigned short* __restrict__ Rb,
                                                       unsigned int* __restrict__ F8,
                                                       float* __restrict__ out,
                                                       float* __restrict__ al4,
                                                       int Kp) {
    const int NW  = MODE ? 512 : 256;
    const int NCB = MODE ? 5 : 4;                     // col blocks
    __shared__ __align__(16) short AsBs[16384];       // As = [0,8192), Bs = [8192,16384)
    __shared__ __align__(16) unsigned short Cs[2][32][132];
    short* As = AsBs;
    short* Bs = AsBs + 8192;

    const int tid = threadIdx.x;
    const int l   = tid & 63;
    const int w   = tid >> 6;
    const int wm  = w >> 1, wn = w & 1;
    const int lrow = l & 15;
    const int lq   = l >> 4;

    // XCD-chunked bijective remap (m204)
    const int T = NCB * 313;
    const int flat = blockIdx.y * NCB + blockIdx.x;
    const int q8 = T >> 3, r8 = T & 7;
    const int xcd = flat & 7, sidx = flat >> 3;
    const int wg = (xcd < r8 ? xcd * (q8 + 1) : r8 * (q8 + 1) + (xcd - r8) * q8) + sidx;
    const int row0 = (wg / NCB) * 128;
    const int col0 = (wg % NCB) * 128;

    float4v acc[4][4] = {};

    // global_load_lds layout: load j, thread t -> LDS elems j*2048 + t*8
    //  == row-major [128][64]: r = j*32 + (t>>3), k = (t&7)*8
    const int lr_ld = tid >> 3;
    const int lk_ld = (tid & 7) * 8;
    const int nk = Kp >> 6;
    for (int t = 0; t < nk; ++t) {
        const int k0 = t << 6;
        if (t) __syncthreads();                       // all waves done reading LDS
        const size_t abase = (size_t)(row0 + lr_ld) * Kp + k0 + lk_ld;
        const size_t bbase = (size_t)(col0 + lr_ld) * Kp + k0 + lk_ld;
        #pragma unroll
        for (int j = 0; j < 4; ++j) {
            gl2lds16(&A[abase + (size_t)j * 32 * Kp],  &As[j * 2048 + tid * 8]);
            gl2lds16(&Bt[bbase + (size_t)j * 32 * Kp], &Bs[j * 2048 + tid * 8]);
        }
        __syncthreads();                              // drains vmcnt -> LDS ready
        #pragma unroll
        for (int ks = 0; ks < 2; ++ks) {
            short8 aF[4], bF[4];
            #pragma unroll
            for (int rt = 0; rt < 4; ++rt)
                aF[rt] = *(const short8*)&As[(wm * 64 + rt * 16 + lrow) * 64 + ks * 32 + lq * 8];
            #pragma unroll
            for (int ct = 0; ct < 4; ++ct)
                bF[ct] = *(const short8*)&Bs[(wn * 64 + ct * 16 + lrow) * 64 + ks * 32 + lq * 8];
            #pragma unroll
            for (int rt = 0; rt < 4; ++rt)
                #pragma unroll
                for (int ct = 0; ct < 4; ++ct)
                    acc[rt][ct] = __builtin_amdgcn_mfma_f32_16x16x32_bf16(aF[rt], bF[ct],
                                                                          acc[rt][ct], 0, 0, 0);
        }
    }

    const int colbase = col0 + wn * 64;           // this wave's 64-col span start
    const bool isW = colbase < NW;

    // ---- al_s / al_d reduction (W-part only; plain stores, no atomics)
    if (isW) {
        const int head = (colbase * NHEAD) / NW;
        const int half = MODE ? ((colbase >> 6) & 1) : 0;
        float* als_o = al4 + (half ? 2 * N4 : 0);
        float* ald_o = als_o + N4;
        float as_c[4], ad_c[4];
        #pragma unroll
        for (int ct = 0; ct < 4; ++ct) {
            int col = colbase + ct * 16 + lrow;
            as_c[ct] = asv[col];
            ad_c[ct] = adv[col];
        }
        #pragma unroll
        for (int rt = 0; rt < 4; ++rt) {
            #pragma unroll
            for (int i = 0; i < 4; ++i) {
                int r = row0 + wm * 64 + rt * 16 + lq * 4 + i;
                float fs = 0.f, fd = 0.f;
                #pragma unroll
                for (int ct = 0; ct < 4; ++ct) {
                    float v = acc[rt][ct][i];
                    fs += v * as_c[ct];
                    fd += v * ad_c[ct];
                }
                #pragma unroll
                for (int o2 = 8; o2; o2 >>= 1) {
                    fs += __shfl_xor(fs, o2, 16);
                    fd += __shfl_xor(fd, o2, 16);
                }
                if (lrow == 0 && r < NNODES) {
                    als_o[r * 4 + head] = fs;
                    ald_o[r * 4 + head] = fd;
                }
            }
        }
    }

    // ---- stores
    const int rp = tid >> 2, g2 = rp >> 5, rr = rp & 31, qq = tid & 3;

    if (MODE == 1 && col0 >= 512) {
        // fp32 out block (121 real cols): stage 32-row slabs in LDS, write
        // 484B-contiguous rows (full-line writes, no RMW inflation)
        float* Ls = (float*)AsBs;                 // [32][132] fp32 = 16.9KB
        #pragma unroll
        for (int p = 0; p < 4; ++p) {
            __syncthreads();                      // Ls free (aliases As/Bs)
            if (wm == (p >> 1)) {
                const int rt0 = (p & 1) * 2;
                #pragma unroll
                for (int rt2 = 0; rt2 < 2; ++rt2) {
                    int rt = rt0 + rt2;
                    #pragma unroll
                    for (int ct = 0; ct < 4; ++ct) {
                        int cl = wn * 64 + ct * 16 + lrow;
                        #pragma unroll
                        for (int i = 0; i < 4; ++i) {
                            int lr = rt2 * 16 + lq * 4 + i;
                            Ls[lr * 132 + cl] = acc[rt][ct][i];
                        }
                    }
                }
            }
            __syncthreads();
            #pragma unroll
            for (int it = 0; it < 16; ++it) {     // 32 rows x 128 cols / 256 thr
                int idx = it * 256 + tid;
                int r = idx >> 7, c = idx & 127;
                int grow = row0 + p * 32 + r;
                if (c < 121 && grow < NNODES)
                    out[(size_t)grow * 121 + c] = Ls[r * 132 + c] + bias[c];
            }
        }
        return;
    }

    if (MODE == 1) {
        // feat block -> F8 directly (bf16 round then fp8 pack)
        #pragma unroll
        for (int p = 0; p < 2; ++p) {
            if (p) __syncthreads();
            #pragma unroll
            for (int rt2 = 0; rt2 < 2; ++rt2) {
                int rt = p * 2 + rt2;
                #pragma unroll
                for (int ct = 0; ct < 4; ++ct) {
                    int cl = wn * 64 + ct * 16 + lrow;
                    #pragma unroll
                    for (int i = 0; i < 4; ++i) {
                        int lr = rt2 * 16 + lq * 4 + i;
                        Cs[wm][lr][cl] = f2bf(acc[rt][ct][i]);
                    }
                }
            }
            __syncthreads();
            int grow = row0 + g2 * 64 + p * 32 + rr;
            if (grow < NNODES) {
                #pragma unroll
                for (int k = 0; k < 4; ++k) {
                    ushort8v v = *(const ushort8v*)&Cs[g2][rr][qq * 32 + 8 * k];
                    int u0 = 0, u1 = 0;
                    u0 = __builtin_amdgcn_cvt_pk_fp8_f32(bf2f(v[0]), bf2f(v[1]), u0, false);
                    u0 = __builtin_amdgcn_cvt_pk_fp8_f32(bf2f(v[2]), bf2f(v[3]), u0, true);
                    u1 = __builtin_amdgcn_cvt_pk_fp8_f32(bf2f(v[4]), bf2f(v[5]), u1, false);
                    u1 = __builtin_amdgcn_cvt_pk_fp8_f32(bf2f(v[6]), bf2f(v[7]), u1, true);
                    uint2v wv; wv.x = (unsigned)u0; wv.y = (unsigned)u1;
                    *(uint2v*)&F8[(size_t)grow * 128 + (col0 >> 2) + qq * 8 + 2 * k] = wv;
                }
            }
        }
        return;
    }

    // MODE 0: bf16 destination (block-uniform)
    const bool isRb = col0 >= 256;
    unsigned short* dest = isRb ? Rb : Fb;
    const int cold = isRb ? col0 - 256 : col0;
    float badd[4] = {0.f, 0.f, 0.f, 0.f};
    if (isRb) {
        #pragma unroll
        for (int ct = 0; ct < 4; ++ct)
            badd[ct] = bias[col0 - 256 + wn * 64 + ct * 16 + lrow];
    }

    #pragma unroll
    for (int p = 0; p < 2; ++p) {
        if (p) __syncthreads();
        #pragma unroll
        for (int rt2 = 0; rt2 < 2; ++rt2) {
            int rt = p * 2 + rt2;
            #pragma unroll
            for (int ct = 0; ct < 4; ++ct) {
                int cl = wn * 64 + ct * 16 + lrow;
                #pragma unroll
                for (int i = 0; i < 4; ++i) {
                    int lr = rt2 * 16 + lq * 4 + i;
                    Cs[wm][lr][cl] = f2bf(acc[rt][ct][i] + badd[ct]);
                }
            }
        }
        __syncthreads();
        int grow = row0 + g2 * 64 + p * 32 + rr;
        if (grow < NNODES) {
            #pragma unroll
            for (int k = 0; k < 4; ++k) {
                ushort8v v = *(const ushort8v*)&Cs[g2][rr][qq * 32 + 8 * k];
                *(ushort8v*)&dest[(size_t)grow * 256 + cold + qq * 32 + 8 * k] = v;
            }
        }
    }
}

// --------------------------------------------------- attn layers 1-2 (C=64, concat)
// wave per node; half-wave (32 lanes) per edge, 2 edges/iter; lane = 8 ch (16B).
// 3-stage pipeline: csr[j+4], feat[src[j+2]], al4[src[j+2]] in flight while edge
// j is FMA'd; exp computed on prefetched operand (off the critical path).
__global__ __launch_bounds__(256) void attn64_kernel(const unsigned short* __restrict__ featb,
                                                     const float* __restrict__ al4,
                                                     const int* __restrict__ offs,
                                                     const int* __restrict__ csr,
                                                     const unsigned short* __restrict__ Rb,
                                                     unsigned short* __restrict__ outb) {
    int n = blockIdx.x * 4 + (threadIdx.x >> 6);
    int l = threadIdx.x & 63;
    int half = l >> 5, li = l & 31;
    int h = li >> 3;                         // 8 lanes/head, 8 ch/lane
    int beg = n ? offs[n - 1] : 0;
    int end = offs[n];
    float d0 = al4[N4 + n * 4 + h];          // ald0[n,h]

    float a[8] = {};
    float s = 0.f;

    int j = beg + half;
    int sn_n = 0;
    ushort8v u_c = {};
    float al_c = 0.f;
    if (j < end) {
        int sn_c = csr[j];
        u_c = *(const ushort8v*)&featb[(size_t)sn_c * 256 + 8 * li];
        al_c = al4[sn_c * 4 + h];
    }
    if (j + 2 < end) sn_n = csr[j + 2];

    for (; j < end; j += 2) {
        int j2 = j + 2;
        int sn_nn = (j2 + 2 < end) ? csr[j2 + 2] : 0;
        ushort8v u_n = *(const ushort8v*)&featb[(size_t)sn_n * 256 + 8 * li];
        float al_n = al4[sn_n * 4 + h];
        float p_c = __expf(lrelu(al_c + d0));
        s += p_c;
        #pragma unroll
        for (int i = 0; i < 8; ++i) a[i] += p_c * bf2f(u_c[i]);
        u_c = u_n; al_c = al_n; sn_n = sn_nn;
    }
    s += __shfl_xor(s, 32, 64);
    #pragma unroll
    for (int i = 0; i < 8; ++i) a[i] += __shfl_xor(a[i], 32, 64);

    // self-loop
    float p0 = __expf(lrelu(al4[n * 4 + h] + d0));
    s += p0;
    {
        ushort8v f = *(const ushort8v*)&featb[(size_t)n * 256 + 8 * li];
        #pragma unroll
        for (int i = 0; i < 8; ++i) a[i] += p0 * bf2f(f[i]);
    }
    if (half == 0) {
        float inv = 1.f / s;
        ushort8v r = *(const ushort8v*)&Rb[(size_t)n * 256 + 8 * li];
        ushort8v o;
        #pragma unroll
        for (int i = 0; i < 8; ++i) o[i] = f2bf(fmaxf(bf2f(r[i]) + a[i] * inv, 0.f));
        *(ushort8v*)&outb[(size_t)n * 256 + 8 * li] = o;
    }
}

// --------------------------------------------------- attn layer 3 (fp8 feat, mean)
// wave per node; half-wave per edge (16B = 16 fp8/lane); HW fp8->f32 decode.
// Reads COMBINED planes (al_combine): alS = plane 2, alD = plane 3.
__global__ __launch_bounds__(256) void attn121_kernel(const unsigned int* __restrict__ F8,
                                                      const float* __restrict__ al4,
                                                      const int* __restrict__ offs,
                                                      const int* __restrict__ csr,
                                                      float* __restrict__ out) {
    int n = blockIdx.x * 4 + (threadIdx.x >> 6);
    int l = threadIdx.x & 63;
    int half = l >> 5, li = l & 31;
    int h = li >> 3;                         // 8 lanes/head, 16 ch/lane (128-pad head)
    int beg = n ? offs[n - 1] : 0;
    int end = offs[n];
    float dD = al4[3 * N4 + n * 4 + h];      // combined ald[n,h]

    float a[16] = {};
    float s = 0.f;

    int j = beg + half;
    int sn_n = 0;
    uint4v u_c = {};
    float al_c = 0.f;
    if (j < end) {
        int sn_c = csr[j];
        u_c = *(const uint4v*)&F8[(size_t)sn_c * 128 + 4 * li];
        al_c = al4[2 * N4 + sn_c * 4 + h];
    }
    if (j + 2 < end) sn_n = csr[j + 2];

    for (; j < end; j += 2) {
        int j2 = j + 2;
        int sn_nn = (j2 + 2 < end) ? csr[j2 + 2] : 0;
        uint4v u_n = *(const uint4v*)&F8[(size_t)sn_n * 128 + 4 * li];
        float al_n = al4[2 * N4 + sn_n * 4 + h];
        float p_c = __expf(lrelu(al_c + dD));
        s += p_c;
        #pragma unroll
        for (int k = 0; k < 4; ++k) {
            float2v lo = __builtin_amdgcn_cvt_pk_f32_fp8(u_c[k], false);
            float2v hi = __builtin_amdgcn_cvt_pk_f32_fp8(u_c[k], true);
            a[4 * k + 0] += p_c * lo.x; a[4 * k + 1] += p_c * lo.y;
            a[4 * k + 2] += p_c * hi.x; a[4 * k + 3] += p_c * hi.y;
        }
        u_c = u_n; al_c = al_n; sn_n = sn_nn;
    }
    s += __shfl_xor(s, 32, 64);
    #pragma unroll
    for (int i = 0; i < 16; ++i) a[i] += __shfl_xor(a[i], 32, 64);

    // self-loop
    float p0 = __expf(lrelu(al4[2 * N4 + n * 4 + h] + dD));
    s += p0;
    {
        uint4v u = *(const uint4v*)&F8[(size_t)n * 128 + 4 * li];
        #pragma unroll
        for (int k = 0; k < 4; ++k) {
            float2v lo = __builtin_amdgcn_cvt_pk_f32_fp8(u[k], false);
            float2v hi = __builtin_amdgcn_cvt_pk_f32_fp8(u[k], true);
            a[4 * k + 0] += p0 * lo.x; a[4 * k + 1] += p0 * lo.y;
            a[4 * k + 2] += p0 * hi.x; a[4 * k + 3] += p0 * hi.y;
        }
    }
    float inv = 0.25f / s;                 // mean over heads
    #pragma unroll
    for (int i = 0; i < 16; ++i) {
        a[i] *= inv;
        a[i] += __shfl_xor(a[i], 8, 64);   // sum 4 head groups (lanes li^8, li^16)
        a[i] += __shfl_xor(a[i], 16, 64);
    }
    if (l < 8) {                           // half 0, head 0 lanes hold channel sums
        #pragma unroll
        for (int i = 0; i < 16; ++i) {
            int c = 16 * l + i;
            if (c < 121) out[(size_t)n * 121 + c] += a[i];
        }
    }
}

// ---------------------------------------------------------------- launch
extern "C" void kernel_launch(void* const* d_in, const int* in_sizes, int n_in,
                              void* d_out, int out_size, void* d_ws, size_t ws_size,
                              hipStream_t stream) {
    const float* x   = (const float*)d_in[0];
    const int* ei    = (const int*)d_in[1];
    const float* W1  = (const float*)d_in[2];
    const float* a1s = (const float*)d_in[3];
    const float* a1d = (const float*)d_in[4];
    const float* Wr1 = (const float*)d_in[5];
    const float* b1  = (const float*)d_in[6];
    const float* W2  = (const float*)d_in[7];
    const float* a2s = (const float*)d_in[8];
    const float* a2d = (const float*)d_in[9];
    const float* Wr2 = (const float*)d_in[10];
    const float* b2  = (const float*)d_in[11];
    const float* W3  = (const float*)d_in[12];
    const float* a3s = (const float*)d_in[13];
    const float* a3d = (const float*)d_in[14];
    const float* Wr3 = (const float*)d_in[15];
    const float* b3  = (const float*)d_in[16];
    float* out = (float*)d_out;

    const int* e_src = ei;
    const int* e_dst = ei + NEDGES;

    char* ws = (char*)d_ws;
    size_t off = 0;
    auto carve = [&](size_t bytes) { void* p = ws + off; off += (bytes + 255) & ~255ull; return p; };
    unsigned short* Fb = (unsigned short*)carve((size_t)MPAD * 256 * 2);
    unsigned short* Rb = (unsigned short*)carve((size_t)MPAD * 256 * 2);
    unsigned short* Hb = (unsigned short*)carve((size_t)MPAD * 256 * 2);
    unsigned int* F8 = (unsigned int*)carve((size_t)NNODES * 128 * 4);
    short* xb   = (short*)carve((size_t)MPAD * 64 * 2);
    short* wc1  = (short*)carve((size_t)512 * 64 * 2);
    short* wc2  = (short*)carve((size_t)512 * 256 * 2);
    short* wc3  = (short*)carve((size_t)640 * 256 * 2);
    float* a3sp = (float*)carve(512 * 4);
    float* a3dp = (float*)carve(512 * 4);
    float* al4  = (float*)carve((size_t)4 * N4 * 4);   // [als0|ald0|alS|alD]
    int* csr_src = (int*)carve((size_t)NEDGES * 4);
    int* offsets = (int*)carve(((size_t)NNODES + 4) * 4);
    int* counts  = (int*)carve((size_t)NNODES * 4);
    int* partials = (int*)carve(256 * 4);
    int* pexcl    = (int*)carve(256 * 4);

    const int EB = (NEDGES + 255) / 256;
    dim3 blk(256);

    // fused init: converts + hist (counts zeroed first)
    hipMemsetAsync(counts, 0, NNODES * 4, stream);
    init_all<<<(R3 + 255) / 256, blk, 0, stream>>>(x, xb, W1, Wr1, W2, Wr2, wc1, wc2,
                                                   W3, Wr3, a3s, a3d, wc3, a3sp, a3dp,
                                                   e_dst, counts);

    // CSR by dst (parallel scan; scatter mutates offsets into end-positions)
    scan_local<<<SCANB, blk, 0, stream>>>(counts, offsets, partials);
    scan_partials<<<1, blk, 0, stream>>>(partials, pexcl);
    scan_carry<<<SCANB, blk, 0, stream>>>(offsets, pexcl);
    scatter_kernel<<<EB, blk, 0, stream>>>(e_src, e_dst, offsets, csr_src, NEDGES);

    // ---- layer 1 (K=64)
    mfma_gemm_fused<0><<<dim3(4, 313), blk, 0, stream>>>(xb, wc1, b1, a1s, a1d,
                                                         Fb, Rb, nullptr, nullptr, al4, 64);
    attn64_kernel<<<NNODES / 4, blk, 0, stream>>>(Fb, al4, offsets, csr_src, Rb, Hb);

    // ---- layer 2 (K=256)
    mfma_gemm_fused<0><<<dim3(4, 313), blk, 0, stream>>>((short*)Hb, wc2, b2, a2s, a2d,
                                                         Fb, Rb, nullptr, nullptr, al4, 256);
    attn64_kernel<<<NNODES / 4, blk, 0, stream>>>(Fb, al4, offsets, csr_src, Rb, Hb);

    // ---- layer 3 (K=256, N=640): feat -> F8 fused, residual+bias -> out
    mfma_gemm_fused<1><<<dim3(5, 313), blk, 0, stream>>>((short*)Hb, wc3, b3, a3sp, a3dp,
                                                         nullptr, nullptr, F8, out, al4, 256);
    al_combine<<<313, blk, 0, stream>>>(al4);
    attn121_kernel<<<NNODES / 4, blk, 0, stream>>>(F8, al4, offsets, csr_src, out);
}